// Round 1
// 400.524 us; speedup vs baseline: 1.0650x; 1.0650x over previous
//
#include <hip/hip_runtime.h>
#include <hip/hip_fp16.h>
#include <cstdint>

// Shapes (hard-coded): B=4, Cx=512, Cy=256, M=64, H=W=64, N=4096
constexpr int N_ = 4096;
constexpr float CNT = 16384.f;  // B*N reduction count for BN stats

typedef __attribute__((ext_vector_type(8))) _Float16 half8;
typedef __attribute__((ext_vector_type(4))) float f32x4;
union fragh { half8 h8; int i4[4]; };

__device__ inline int pkh(float a, float b) {
  union { __half2 h; int i; } u;
  u.h = __float22half2_rn(float2{a, b});
  return u.i;
}

// Stats layout (floats): group g in {0:s1,1:x1,2:y1,3:s2,4:x2,5:y2}:
//   sum at g*128+c, sumsq at g*128+64+c (c<64). f_up: sum 768+c, sumsq 1280+c.

// ---------------- stage-1 convs: SGEMM tiling, 64o x 128n tile, 8x4/thread ---------
__global__ __launch_bounds__(256) void conv1_k(
    const float* __restrict__ x, const float* __restrict__ y,
    const float* __restrict__ ws1, const float* __restrict__ wx1,
    const float* __restrict__ wy1,
    float* __restrict__ z1s, float* __restrict__ z1x, float* __restrict__ z1y,
    float* __restrict__ stats) {
  const int t = threadIdx.x;
  const int slice = blockIdx.x;  // 0..127
  const int b = slice >> 5;
  const int n0 = (slice & 31) * 128;
  const int branch = blockIdx.y;  // 0:s 1:x 2:y
  const float* A = branch == 2 ? y : x;
  const float* W = branch == 0 ? ws1 : (branch == 1 ? wx1 : wy1);
  float* out = branch == 0 ? z1s : (branch == 1 ? z1x : z1y);
  const int K = branch == 2 ? 256 : 512;
  float* st = stats + branch * 128;

  __shared__ float sA[32][132];
  __shared__ float sW[32][72];

  const int to = (t >> 5) * 8;
  const int tn = (t & 31) * 4;
  float acc[8][4];
#pragma unroll
  for (int i = 0; i < 8; ++i)
#pragma unroll
    for (int j = 0; j < 4; ++j) acc[i][j] = 0.f;

  const float* Ab = A + (size_t)b * K * N_ + n0;
#pragma unroll 1
  for (int k0 = 0; k0 < K; k0 += 32) {
    __syncthreads();
#pragma unroll
    for (int i = 0; i < 4; ++i) {
      int row = i * 8 + (t >> 5);
      float4 v = *(const float4*)&Ab[(size_t)(k0 + row) * N_ + tn];
      *(float4*)&sA[row][tn] = v;
    }
    {
      int o = t >> 2, kk = (t & 3) * 8;
      float4 w0 = *(const float4*)&W[(size_t)o * K + k0 + kk];
      float4 w1 = *(const float4*)&W[(size_t)o * K + k0 + kk + 4];
      sW[kk + 0][o] = w0.x; sW[kk + 1][o] = w0.y;
      sW[kk + 2][o] = w0.z; sW[kk + 3][o] = w0.w;
      sW[kk + 4][o] = w1.x; sW[kk + 5][o] = w1.y;
      sW[kk + 6][o] = w1.z; sW[kk + 7][o] = w1.w;
    }
    __syncthreads();
#pragma unroll
    for (int k = 0; k < 32; ++k) {
      float4 a = *(const float4*)&sA[k][tn];
      float4 w0 = *(const float4*)&sW[k][to];
      float4 w1 = *(const float4*)&sW[k][to + 4];
      float wv[8] = {w0.x, w0.y, w0.z, w0.w, w1.x, w1.y, w1.z, w1.w};
      float av[4] = {a.x, a.y, a.z, a.w};
#pragma unroll
      for (int i = 0; i < 8; ++i)
#pragma unroll
        for (int j = 0; j < 4; ++j) acc[i][j] += wv[i] * av[j];
    }
  }
  float* Cb = out + (size_t)b * 64 * N_ + n0;
#pragma unroll
  for (int i = 0; i < 8; ++i) {
    float4 v = {acc[i][0], acc[i][1], acc[i][2], acc[i][3]};
    *(float4*)&Cb[(size_t)(to + i) * N_ + tn] = v;
  }
#pragma unroll
  for (int i = 0; i < 8; ++i) {
    float s = acc[i][0] + acc[i][1] + acc[i][2] + acc[i][3];
    float q = acc[i][0] * acc[i][0] + acc[i][1] * acc[i][1] +
              acc[i][2] * acc[i][2] + acc[i][3] * acc[i][3];
#pragma unroll
    for (int d = 1; d < 32; d <<= 1) { s += __shfl_xor(s, d); q += __shfl_xor(q, d); }
    if ((t & 31) == 0) { atomicAdd(&st[to + i], s); atomicAdd(&st[64 + to + i], q); }
  }
}

// ---------------- stage-2 convs (K=64), BN1 applied during A staging ---------------
__global__ __launch_bounds__(256) void conv2_k(
    const float* __restrict__ z1s, const float* __restrict__ z1x,
    const float* __restrict__ z1y,
    const float* __restrict__ ws2, const float* __restrict__ wx2,
    const float* __restrict__ wy2,
    const float* __restrict__ gs1, const float* __restrict__ bs1,
    const float* __restrict__ gx1, const float* __restrict__ bx1,
    const float* __restrict__ gy1, const float* __restrict__ by1,
    float* __restrict__ z2s, float* __restrict__ z2x, float* __restrict__ z2y,
    float* __restrict__ stats) {
  const int t = threadIdx.x;
  const int slice = blockIdx.x;
  const int b = slice >> 5;
  const int n0 = (slice & 31) * 128;
  const int branch = blockIdx.y;
  const float* A = branch == 0 ? z1s : (branch == 1 ? z1x : z1y);
  const float* W = branch == 0 ? ws2 : (branch == 1 ? wx2 : wy2);
  const float* g1 = branch == 0 ? gs1 : (branch == 1 ? gx1 : gy1);
  const float* b1 = branch == 0 ? bs1 : (branch == 1 ? bx1 : by1);
  float* out = branch == 0 ? z2s : (branch == 1 ? z2x : z2y);
  const float* stin = stats + branch * 128;
  float* stout = stats + (3 + branch) * 128;

  __shared__ float sA[32][132];
  __shared__ float sW[32][72];
  __shared__ float sc[64], sh[64];

  if (t < 64) {
    float mean = stin[t] * (1.f / CNT);
    float var = stin[64 + t] * (1.f / CNT) - mean * mean;
    float r = rsqrtf(var + 1e-5f);
    float s = g1[t] * r;
    sc[t] = s;
    sh[t] = b1[t] - mean * s;
  }

  const int to = (t >> 5) * 8;
  const int tn = (t & 31) * 4;
  float acc[8][4];
#pragma unroll
  for (int i = 0; i < 8; ++i)
#pragma unroll
    for (int j = 0; j < 4; ++j) acc[i][j] = 0.f;

  const float* Ab = A + (size_t)b * 64 * N_ + n0;
#pragma unroll 1
  for (int k0 = 0; k0 < 64; k0 += 32) {
    __syncthreads();
#pragma unroll
    for (int i = 0; i < 4; ++i) {
      int row = i * 8 + (t >> 5);
      float4 v = *(const float4*)&Ab[(size_t)(k0 + row) * N_ + tn];
      float s = sc[k0 + row], h = sh[k0 + row];
      v.x = v.x * s + h; v.y = v.y * s + h; v.z = v.z * s + h; v.w = v.w * s + h;
      *(float4*)&sA[row][tn] = v;
    }
    {
      int o = t >> 2, kk = (t & 3) * 8;
      float4 w0 = *(const float4*)&W[(size_t)o * 64 + k0 + kk];
      float4 w1 = *(const float4*)&W[(size_t)o * 64 + k0 + kk + 4];
      sW[kk + 0][o] = w0.x; sW[kk + 1][o] = w0.y;
      sW[kk + 2][o] = w0.z; sW[kk + 3][o] = w0.w;
      sW[kk + 4][o] = w1.x; sW[kk + 5][o] = w1.y;
      sW[kk + 6][o] = w1.z; sW[kk + 7][o] = w1.w;
    }
    __syncthreads();
#pragma unroll
    for (int k = 0; k < 32; ++k) {
      float4 a = *(const float4*)&sA[k][tn];
      float4 w0 = *(const float4*)&sW[k][to];
      float4 w1 = *(const float4*)&sW[k][to + 4];
      float wv[8] = {w0.x, w0.y, w0.z, w0.w, w1.x, w1.y, w1.z, w1.w};
      float av[4] = {a.x, a.y, a.z, a.w};
#pragma unroll
      for (int i = 0; i < 8; ++i)
#pragma unroll
        for (int j = 0; j < 4; ++j) acc[i][j] += wv[i] * av[j];
    }
  }
  float* Cb = out + (size_t)b * 64 * N_ + n0;
#pragma unroll
  for (int i = 0; i < 8; ++i) {
    float4 v = {acc[i][0], acc[i][1], acc[i][2], acc[i][3]};
    *(float4*)&Cb[(size_t)(to + i) * N_ + tn] = v;
  }
#pragma unroll
  for (int i = 0; i < 8; ++i) {
    float s = acc[i][0] + acc[i][1] + acc[i][2] + acc[i][3];
    float q = acc[i][0] * acc[i][0] + acc[i][1] * acc[i][1] +
              acc[i][2] * acc[i][2] + acc[i][3] * acc[i][3];
#pragma unroll
    for (int d = 1; d < 32; d <<= 1) { s += __shfl_xor(s, d); q += __shfl_xor(q, d); }
    if ((t & 31) == 0) { atomicAdd(&stout[to + i], s); atomicAdd(&stout[64 + to + i], q); }
  }
}

// ---------------- pack Q/K/V to fp16 packed-pair planar with inline stage-2 BN -----
__global__ __launch_bounds__(256) void pack_k(
    const float* __restrict__ z2s, const float* __restrict__ z2x,
    const float* __restrict__ z2y,
    const float* __restrict__ gs2, const float* __restrict__ bs2,
    const float* __restrict__ gx2, const float* __restrict__ bx2,
    const float* __restrict__ gy2, const float* __restrict__ by2,
    int* __restrict__ Qh, int* __restrict__ Kh, int* __restrict__ Vp,
    const float* __restrict__ stats) {
  const int job = blockIdx.z;  // 0: Q<-x2, 1: K<-y2, 2: V<-s2
  const int idx = blockIdx.x * 256 + threadIdx.x;  // 0..524287
  const float* z2 = job == 0 ? z2x : (job == 1 ? z2y : z2s);
  const float* g2 = job == 0 ? gx2 : (job == 1 ? gy2 : gs2);
  const float* b2 = job == 0 ? bx2 : (job == 1 ? by2 : bs2);
  const float* st = stats + (job == 0 ? 4 : (job == 1 ? 5 : 3)) * 128;
  int* outp = job == 0 ? Qh : (job == 1 ? Kh : Vp);

  auto snorm = [&](int c, float& s, float& h) {
    float mean = st[c] * (1.f / CNT);
    float var = st[64 + c] * (1.f / CNT) - mean * mean;
    float r = rsqrtf(var + 1e-5f);
    s = g2[c] * r;
    h = b2[c] - mean * s;
  };
  if (job < 2) {
    int n = idx & 4095, c = (idx >> 12) & 31, b = idx >> 17;
    float s0, h0, s1, h1;
    snorm(2 * c, s0, h0);
    snorm(2 * c + 1, s1, h1);
    float v0 = z2[((size_t)b * 64 + 2 * c) * N_ + n] * s0 + h0;
    float v1 = z2[((size_t)b * 64 + 2 * c + 1) * N_ + n] * s1 + h1;
    outp[idx] = pkh(v0, v1);
  } else {
    int k = idx & 2047, ch = (idx >> 11) & 63, b = idx >> 17;
    float s0, h0;
    snorm(ch, s0, h0);
    float2 v = *(const float2*)&z2[((size_t)b * 64 + ch) * N_ + 2 * k];
    outp[idx] = pkh(v.x * s0 + h0, v.y * s0 + h0);
  }
}

// ---------------- MFMA fp16 flash attention, swapped-operand S^T layout ------------
// QK^T computed as mfma(K,Q) -> S^T[key][query]: col(lane&15)=query, so each lane
// owns 8 key-scores of ONE query. Softmax row-reduce = in-lane max/sum + 2
// shfl_xor(16/32) instead of 4-row x 8-shuffle chains (32 ds ops -> 4 per iter).
// PV computed as mfma(V, P^T) -> O^T[m][q], which is fout's natural [m][n] layout.
// P^T redistribution between quads goes through a tiny padded LDS table
// (4 b32 writes + 4 b32 reads per lane per 32 keys, 2-way-free banking).
__global__ __launch_bounds__(256) void attn_k(const int* __restrict__ Qh,
                                              const int* __restrict__ Kh,
                                              const int* __restrict__ Vp,
                                              float* __restrict__ fout) {
  const int tid = threadIdx.x;
  const int lane = tid & 63;
  const int wid = tid >> 6;
  const int la = lane & 15;
  const int quad = lane >> 4;
  const int b = blockIdx.x & 3;
  const int qbase = (blockIdx.x >> 2) * 16;
  const int* Qb = Qh + (size_t)b * 32 * N_;
  const int* Kb = Kh + (size_t)b * 32 * N_;
  const int* Vb = Vp + (size_t)b * 64 * 2048;

  __shared__ union USm {
    int P16[4][16 * 20];  // per-wave packed P^T pairs: [pair 0..15][q 0..15] pad 20
    struct { float O[4][16][68]; float M[4][16]; float L[4][16]; } e;
  } smu;
  int* myP = smu.P16[wid];

  // Q fragment (B operand now): col=lane&15=query qbase+la, k=channels
  fragh aq[2];
#pragma unroll
  for (int c = 0; c < 2; ++c)
#pragma unroll
    for (int j = 0; j < 4; ++j)
      aq[c].i4[j] = Qb[(size_t)(c * 16 + quad * 4 + j) * N_ + qbase + la];

  f32x4 o[4];
  float mrun = -3.0e38f, lrun = 0.f;
#pragma unroll
  for (int mt = 0; mt < 4; ++mt) o[mt] = f32x4{0.f, 0.f, 0.f, 0.f};

  const int jbeg = wid * (N_ / 4);
#pragma unroll 1
  for (int j0 = jbeg; j0 < jbeg + N_ / 4; j0 += 32) {
    // S^T tiles: s[nt][r] = S[key = j0+nt*16+quad*4+r][query = qbase+la]
    f32x4 s[2];
#pragma unroll
    for (int nt = 0; nt < 2; ++nt) {
      fragh k0, k1;
      const int key = j0 + nt * 16 + la;
#pragma unroll
      for (int jj = 0; jj < 4; ++jj) {
        k0.i4[jj] = Kb[(size_t)(quad * 4 + jj) * N_ + key];
        k1.i4[jj] = Kb[(size_t)(16 + quad * 4 + jj) * N_ + key];
      }
      f32x4 z = f32x4{0.f, 0.f, 0.f, 0.f};
      z = __builtin_amdgcn_mfma_f32_16x16x32_f16(k0.h8, aq[0].h8, z, 0, 0, 0);
      s[nt] = __builtin_amdgcn_mfma_f32_16x16x32_f16(k1.h8, aq[1].h8, z, 0, 0, 0);
    }
    // online softmax for query la: in-lane over 8 scores, then cross-quad
    float t0 = fmaxf(fmaxf(s[0][0], s[0][1]), fmaxf(s[0][2], s[0][3]));
    float t1 = fmaxf(fmaxf(s[1][0], s[1][1]), fmaxf(s[1][2], s[1][3]));
    float t = fmaxf(t0, t1);
    t = fmaxf(t, __shfl_xor(t, 16));
    t = fmaxf(t, __shfl_xor(t, 32));
    float mnew = fmaxf(mrun, t);
    float alpha = __expf(mrun - mnew);
    float p[2][4];
    float ps = 0.f;
#pragma unroll
    for (int nt = 0; nt < 2; ++nt)
#pragma unroll
      for (int r = 0; r < 4; ++r) {
        p[nt][r] = __expf(s[nt][r] - mnew);
        ps += p[nt][r];
      }
    ps += __shfl_xor(ps, 16);
    ps += __shfl_xor(ps, 32);
    lrun = lrun * alpha + ps;
    mrun = mnew;
    // pack P^T pairs (even key in low half) and redistribute across quads via LDS
    // write: lane holds key pairs {2quad, 2quad+1} (+8 for nt=1), column la
#pragma unroll
    for (int nt = 0; nt < 2; ++nt) {
      myP[(nt * 8 + quad * 2 + 0) * 20 + la] = pkh(p[nt][0], p[nt][1]);
      myP[(nt * 8 + quad * 2 + 1) * 20 + la] = pkh(p[nt][2], p[nt][3]);
    }
    __asm__ __volatile__("s_waitcnt lgkmcnt(0)" ::: "memory");
    // read B fragment: lane needs key pairs {quad*4+j}, column la
    fragh pb;
#pragma unroll
    for (int j = 0; j < 4; ++j) pb.i4[j] = myP[(quad * 4 + j) * 20 + la];
    // rescale O^T by scalar alpha and accumulate PV^T
#pragma unroll
    for (int mt = 0; mt < 4; ++mt) {
      o[mt][0] *= alpha; o[mt][1] *= alpha;
      o[mt][2] *= alpha; o[mt][3] *= alpha;
    }
#pragma unroll
    for (int mt = 0; mt < 4; ++mt) {
      const int4 vv = *(const int4*)&Vb[(size_t)(mt * 16 + la) * 2048 + (j0 >> 1) + quad * 4];
      fragh vb;
      vb.i4[0] = vv.x; vb.i4[1] = vv.y; vb.i4[2] = vv.z; vb.i4[3] = vv.w;
      o[mt] = __builtin_amdgcn_mfma_f32_16x16x32_f16(vb.h8, pb.h8, o[mt], 0, 0, 0);
    }
  }

  __syncthreads();
  if (quad == 0) {
    smu.e.M[wid][la] = mrun;
    smu.e.L[wid][la] = lrun;
  }
  // O^T: o[mt][r] = O[m = mt*16+quad*4+r][q = la]
#pragma unroll
  for (int mt = 0; mt < 4; ++mt)
#pragma unroll
    for (int r = 0; r < 4; ++r) smu.e.O[wid][la][mt * 16 + quad * 4 + r] = o[mt][r];
  __syncthreads();

#pragma unroll
  for (int t = 0; t < 4; ++t) {
    int oidx = t * 256 + tid;
    int m = oidx >> 4;
    int q = oidx & 15;
    float m0 = fmaxf(fmaxf(smu.e.M[0][q], smu.e.M[1][q]),
                     fmaxf(smu.e.M[2][q], smu.e.M[3][q]));
    float num = 0.f, den = 0.f;
#pragma unroll
    for (int w = 0; w < 4; ++w) {
      float wgt = __expf(smu.e.M[w][q] - m0);
      num += wgt * smu.e.O[w][q][m];
      den += wgt * smu.e.L[w][q];
    }
    fout[((size_t)b * 64 + m) * N_ + qbase + q] = num / den;
  }
}

// ---------------- f_up conv (K=64, O=512): SGEMM tiling ----------------------------
__global__ __launch_bounds__(256) void convup_k(const float* __restrict__ fout,
                                                const float* __restrict__ wu,
                                                float* __restrict__ u,
                                                float* __restrict__ stats) {
  const int t = threadIdx.x;
  const int slice = blockIdx.x;
  const int b = slice >> 5;
  const int n0 = (slice & 31) * 128;
  const int o0 = blockIdx.y * 64;

  __shared__ float sA[32][132];
  __shared__ float sW[32][72];

  const int to = (t >> 5) * 8;
  const int tn = (t & 31) * 4;
  float acc[8][4];
#pragma unroll
  for (int i = 0; i < 8; ++i)
#pragma unroll
    for (int j = 0; j < 4; ++j) acc[i][j] = 0.f;

  const float* Ab = fout + (size_t)b * 64 * N_ + n0;
#pragma unroll 1
  for (int k0 = 0; k0 < 64; k0 += 32) {
    __syncthreads();
#pragma unroll
    for (int i = 0; i < 4; ++i) {
      int row = i * 8 + (t >> 5);
      float4 v = *(const float4*)&Ab[(size_t)(k0 + row) * N_ + tn];
      *(float4*)&sA[row][tn] = v;
    }
    {
      int o = t >> 2, kk = (t & 3) * 8;
      float4 w0 = *(const float4*)&wu[(size_t)(o0 + o) * 64 + k0 + kk];
      float4 w1 = *(const float4*)&wu[(size_t)(o0 + o) * 64 + k0 + kk + 4];
      sW[kk + 0][o] = w0.x; sW[kk + 1][o] = w0.y;
      sW[kk + 2][o] = w0.z; sW[kk + 3][o] = w0.w;
      sW[kk + 4][o] = w1.x; sW[kk + 5][o] = w1.y;
      sW[kk + 6][o] = w1.z; sW[kk + 7][o] = w1.w;
    }
    __syncthreads();
#pragma unroll
    for (int k = 0; k < 32; ++k) {
      float4 a = *(const float4*)&sA[k][tn];
      float4 w0 = *(const float4*)&sW[k][to];
      float4 w1 = *(const float4*)&sW[k][to + 4];
      float wv[8] = {w0.x, w0.y, w0.z, w0.w, w1.x, w1.y, w1.z, w1.w};
      float av[4] = {a.x, a.y, a.z, a.w};
#pragma unroll
      for (int i = 0; i < 8; ++i)
#pragma unroll
        for (int j = 0; j < 4; ++j) acc[i][j] += wv[i] * av[j];
    }
  }
  float* Cb = u + ((size_t)b * 512 + o0) * N_ + n0;
#pragma unroll
  for (int i = 0; i < 8; ++i) {
    float4 v = {acc[i][0], acc[i][1], acc[i][2], acc[i][3]};
    *(float4*)&Cb[(size_t)(to + i) * N_ + tn] = v;
  }
#pragma unroll
  for (int i = 0; i < 8; ++i) {
    float s = acc[i][0] + acc[i][1] + acc[i][2] + acc[i][3];
    float q = acc[i][0] * acc[i][0] + acc[i][1] * acc[i][1] +
              acc[i][2] * acc[i][2] + acc[i][3] * acc[i][3];
#pragma unroll
    for (int d = 1; d < 32; d <<= 1) { s += __shfl_xor(s, d); q += __shfl_xor(q, d); }
    if ((t & 31) == 0) {
      atomicAdd(&stats[768 + o0 + to + i], s);
      atomicAdd(&stats[1280 + o0 + to + i], q);
    }
  }
}

// ---------------- residual + final BN ----------------------------------------------
__global__ __launch_bounds__(256) void final_k(const float* __restrict__ x,
                                               const float* __restrict__ u,
                                               const float* __restrict__ gu,
                                               const float* __restrict__ bu,
                                               const float* __restrict__ stats,
                                               float* __restrict__ out) {
  size_t idx = (size_t)blockIdx.x * 256 + threadIdx.x;
  int c = (int)((idx >> 12) & 511);
  float mean = stats[768 + c] * (1.f / CNT);
  float var = stats[1280 + c] * (1.f / CNT) - mean * mean;
  float r = rsqrtf(var + 1e-5f);
  float s = gu[c] * r;
  float sh = bu[c] - mean * s;
  out[idx] = x[idx] + u[idx] * s + sh;
}

extern "C" void kernel_launch(void* const* d_in, const int* in_sizes, int n_in,
                              void* d_out, int out_size, void* d_ws, size_t ws_size,
                              hipStream_t stream) {
  const float* x = (const float*)d_in[0];
  const float* y = (const float*)d_in[1];
  const float* ws1 = (const float*)d_in[2];
  const float* gs1 = (const float*)d_in[3];
  const float* bs1 = (const float*)d_in[4];
  const float* ws2 = (const float*)d_in[5];
  const float* gs2 = (const float*)d_in[6];
  const float* bs2 = (const float*)d_in[7];
  const float* wx1 = (const float*)d_in[8];
  const float* gx1 = (const float*)d_in[9];
  const float* bx1 = (const float*)d_in[10];
  const float* wx2 = (const float*)d_in[11];
  const float* gx2 = (const float*)d_in[12];
  const float* bx2 = (const float*)d_in[13];
  const float* wy1 = (const float*)d_in[14];
  const float* gy1 = (const float*)d_in[15];
  const float* by1 = (const float*)d_in[16];
  const float* wy2 = (const float*)d_in[17];
  const float* gy2 = (const float*)d_in[18];
  const float* by2 = (const float*)d_in[19];
  const float* wu = (const float*)d_in[20];
  const float* gu = (const float*)d_in[21];
  const float* bu = (const float*)d_in[22];
  float* out = (float*)d_out;

  float* w = (float*)d_ws;
  const size_t M1 = 1048576;
  float* z1s = w + 0 * M1;
  float* z1x = w + 1 * M1;
  float* z1y = w + 2 * M1;
  float* z2s = w + 3 * M1;
  float* z2x = w + 4 * M1;
  float* z2y = w + 5 * M1;
  float* fout = w + 6 * M1;
  float* u = w + 7 * M1;  // [4][512][4096] = 8 M floats
  int* Qh = (int*)(w + 15 * M1);
  int* Kh = Qh + 524288;
  int* Vp = Kh + 524288;
  float* stats = (float*)(Vp + 524288);

  hipMemsetAsync(stats, 0, 1792 * sizeof(float), stream);

  conv1_k<<<dim3(128, 3), dim3(256), 0, stream>>>(x, y, ws1, wx1, wy1, z1s, z1x,
                                                  z1y, stats);
  conv2_k<<<dim3(128, 3), dim3(256), 0, stream>>>(
      z1s, z1x, z1y, ws2, wx2, wy2, gs1, bs1, gx1, bx1, gy1, by1, z2s, z2x, z2y,
      stats);
  pack_k<<<dim3(2048, 1, 3), dim3(256), 0, stream>>>(z2s, z2x, z2y, gs2, bs2, gx2,
                                                     bx2, gy2, by2, Qh, Kh, Vp,
                                                     stats);
  attn_k<<<dim3(1024), dim3(256), 0, stream>>>(Qh, Kh, Vp, fout);
  convup_k<<<dim3(128, 8), dim3(256), 0, stream>>>(fout, wu, u, stats);
  final_k<<<dim3(32768), dim3(256), 0, stream>>>(x, u, gu, bu, stats, out);
}

// Round 2
// 365.809 us; speedup vs baseline: 1.1661x; 1.0949x over previous
//
#include <hip/hip_runtime.h>
#include <hip/hip_fp16.h>
#include <cstdint>

// Shapes (hard-coded): B=4, Cx=512, Cy=256, M=64, H=W=64, N=4096
constexpr int N_ = 4096;
constexpr float CNT = 16384.f;  // B*N reduction count for BN stats

typedef __attribute__((ext_vector_type(8))) _Float16 half8;
typedef __attribute__((ext_vector_type(4))) float f32x4;
union fragh { half8 h8; int i4[4]; };

__device__ inline int pkh(float a, float b) {
  union { __half2 h; int i; } u;
  u.h = __float22half2_rn(float2{a, b});
  return u.i;
}

// Stats layout (floats): group g in {0:s1,1:x1,2:y1,3:s2,4:x2,5:y2}:
//   sum at g*128+c, sumsq at g*128+64+c (c<64). f_up: sum 768+c, sumsq 1280+c.

// ---------------- stage-1 convs: SGEMM tiling, 64o x 128n tile, 8x4/thread ---------
__global__ __launch_bounds__(256) void conv1_k(
    const float* __restrict__ x, const float* __restrict__ y,
    const float* __restrict__ ws1, const float* __restrict__ wx1,
    const float* __restrict__ wy1,
    float* __restrict__ z1s, float* __restrict__ z1x, float* __restrict__ z1y,
    float* __restrict__ stats) {
  const int t = threadIdx.x;
  const int slice = blockIdx.x;  // 0..127
  const int b = slice >> 5;
  const int n0 = (slice & 31) * 128;
  const int branch = blockIdx.y;  // 0:s 1:x 2:y
  const float* A = branch == 2 ? y : x;
  const float* W = branch == 0 ? ws1 : (branch == 1 ? wx1 : wy1);
  float* out = branch == 0 ? z1s : (branch == 1 ? z1x : z1y);
  const int K = branch == 2 ? 256 : 512;
  float* st = stats + branch * 128;

  __shared__ float sA[32][132];
  __shared__ float sW[32][72];

  const int to = (t >> 5) * 8;
  const int tn = (t & 31) * 4;
  float acc[8][4];
#pragma unroll
  for (int i = 0; i < 8; ++i)
#pragma unroll
    for (int j = 0; j < 4; ++j) acc[i][j] = 0.f;

  const float* Ab = A + (size_t)b * K * N_ + n0;
#pragma unroll 1
  for (int k0 = 0; k0 < K; k0 += 32) {
    __syncthreads();
#pragma unroll
    for (int i = 0; i < 4; ++i) {
      int row = i * 8 + (t >> 5);
      float4 v = *(const float4*)&Ab[(size_t)(k0 + row) * N_ + tn];
      *(float4*)&sA[row][tn] = v;
    }
    {
      int o = t >> 2, kk = (t & 3) * 8;
      float4 w0 = *(const float4*)&W[(size_t)o * K + k0 + kk];
      float4 w1 = *(const float4*)&W[(size_t)o * K + k0 + kk + 4];
      sW[kk + 0][o] = w0.x; sW[kk + 1][o] = w0.y;
      sW[kk + 2][o] = w0.z; sW[kk + 3][o] = w0.w;
      sW[kk + 4][o] = w1.x; sW[kk + 5][o] = w1.y;
      sW[kk + 6][o] = w1.z; sW[kk + 7][o] = w1.w;
    }
    __syncthreads();
#pragma unroll
    for (int k = 0; k < 32; ++k) {
      float4 a = *(const float4*)&sA[k][tn];
      float4 w0 = *(const float4*)&sW[k][to];
      float4 w1 = *(const float4*)&sW[k][to + 4];
      float wv[8] = {w0.x, w0.y, w0.z, w0.w, w1.x, w1.y, w1.z, w1.w};
      float av[4] = {a.x, a.y, a.z, a.w};
#pragma unroll
      for (int i = 0; i < 8; ++i)
#pragma unroll
        for (int j = 0; j < 4; ++j) acc[i][j] += wv[i] * av[j];
    }
  }
  float* Cb = out + (size_t)b * 64 * N_ + n0;
#pragma unroll
  for (int i = 0; i < 8; ++i) {
    float4 v = {acc[i][0], acc[i][1], acc[i][2], acc[i][3]};
    *(float4*)&Cb[(size_t)(to + i) * N_ + tn] = v;
  }
#pragma unroll
  for (int i = 0; i < 8; ++i) {
    float s = acc[i][0] + acc[i][1] + acc[i][2] + acc[i][3];
    float q = acc[i][0] * acc[i][0] + acc[i][1] * acc[i][1] +
              acc[i][2] * acc[i][2] + acc[i][3] * acc[i][3];
#pragma unroll
    for (int d = 1; d < 32; d <<= 1) { s += __shfl_xor(s, d); q += __shfl_xor(q, d); }
    if ((t & 31) == 0) { atomicAdd(&st[to + i], s); atomicAdd(&st[64 + to + i], q); }
  }
}

// ---------------- stage-2 convs (K=64), BN1 applied during A staging ---------------
__global__ __launch_bounds__(256) void conv2_k(
    const float* __restrict__ z1s, const float* __restrict__ z1x,
    const float* __restrict__ z1y,
    const float* __restrict__ ws2, const float* __restrict__ wx2,
    const float* __restrict__ wy2,
    const float* __restrict__ gs1, const float* __restrict__ bs1,
    const float* __restrict__ gx1, const float* __restrict__ bx1,
    const float* __restrict__ gy1, const float* __restrict__ by1,
    float* __restrict__ z2s, float* __restrict__ z2x, float* __restrict__ z2y,
    float* __restrict__ stats) {
  const int t = threadIdx.x;
  const int slice = blockIdx.x;
  const int b = slice >> 5;
  const int n0 = (slice & 31) * 128;
  const int branch = blockIdx.y;
  const float* A = branch == 0 ? z1s : (branch == 1 ? z1x : z1y);
  const float* W = branch == 0 ? ws2 : (branch == 1 ? wx2 : wy2);
  const float* g1 = branch == 0 ? gs1 : (branch == 1 ? gx1 : gy1);
  const float* b1 = branch == 0 ? bs1 : (branch == 1 ? bx1 : by1);
  float* out = branch == 0 ? z2s : (branch == 1 ? z2x : z2y);
  const float* stin = stats + branch * 128;
  float* stout = stats + (3 + branch) * 128;

  __shared__ float sA[32][132];
  __shared__ float sW[32][72];
  __shared__ float sc[64], sh[64];

  if (t < 64) {
    float mean = stin[t] * (1.f / CNT);
    float var = stin[64 + t] * (1.f / CNT) - mean * mean;
    float r = rsqrtf(var + 1e-5f);
    float s = g1[t] * r;
    sc[t] = s;
    sh[t] = b1[t] - mean * s;
  }

  const int to = (t >> 5) * 8;
  const int tn = (t & 31) * 4;
  float acc[8][4];
#pragma unroll
  for (int i = 0; i < 8; ++i)
#pragma unroll
    for (int j = 0; j < 4; ++j) acc[i][j] = 0.f;

  const float* Ab = A + (size_t)b * 64 * N_ + n0;
#pragma unroll 1
  for (int k0 = 0; k0 < 64; k0 += 32) {
    __syncthreads();
#pragma unroll
    for (int i = 0; i < 4; ++i) {
      int row = i * 8 + (t >> 5);
      float4 v = *(const float4*)&Ab[(size_t)(k0 + row) * N_ + tn];
      float s = sc[k0 + row], h = sh[k0 + row];
      v.x = v.x * s + h; v.y = v.y * s + h; v.z = v.z * s + h; v.w = v.w * s + h;
      *(float4*)&sA[row][tn] = v;
    }
    {
      int o = t >> 2, kk = (t & 3) * 8;
      float4 w0 = *(const float4*)&W[(size_t)o * 64 + k0 + kk];
      float4 w1 = *(const float4*)&W[(size_t)o * 64 + k0 + kk + 4];
      sW[kk + 0][o] = w0.x; sW[kk + 1][o] = w0.y;
      sW[kk + 2][o] = w0.z; sW[kk + 3][o] = w0.w;
      sW[kk + 4][o] = w1.x; sW[kk + 5][o] = w1.y;
      sW[kk + 6][o] = w1.z; sW[kk + 7][o] = w1.w;
    }
    __syncthreads();
#pragma unroll
    for (int k = 0; k < 32; ++k) {
      float4 a = *(const float4*)&sA[k][tn];
      float4 w0 = *(const float4*)&sW[k][to];
      float4 w1 = *(const float4*)&sW[k][to + 4];
      float wv[8] = {w0.x, w0.y, w0.z, w0.w, w1.x, w1.y, w1.z, w1.w};
      float av[4] = {a.x, a.y, a.z, a.w};
#pragma unroll
      for (int i = 0; i < 8; ++i)
#pragma unroll
        for (int j = 0; j < 4; ++j) acc[i][j] += wv[i] * av[j];
    }
  }
  float* Cb = out + (size_t)b * 64 * N_ + n0;
#pragma unroll
  for (int i = 0; i < 8; ++i) {
    float4 v = {acc[i][0], acc[i][1], acc[i][2], acc[i][3]};
    *(float4*)&Cb[(size_t)(to + i) * N_ + tn] = v;
  }
#pragma unroll
  for (int i = 0; i < 8; ++i) {
    float s = acc[i][0] + acc[i][1] + acc[i][2] + acc[i][3];
    float q = acc[i][0] * acc[i][0] + acc[i][1] * acc[i][1] +
              acc[i][2] * acc[i][2] + acc[i][3] * acc[i][3];
#pragma unroll
    for (int d = 1; d < 32; d <<= 1) { s += __shfl_xor(s, d); q += __shfl_xor(q, d); }
    if ((t & 31) == 0) { atomicAdd(&stout[to + i], s); atomicAdd(&stout[64 + to + i], q); }
  }
}

// ---------------- pack Q/K/V to fp16 with inline stage-2 BN ------------------------
// Q stays planar pair-planes (loaded once per attn block, gather cost negligible).
// K and V are written in exact MFMA fragment order so that every K/V access in the
// attention K-loop is one fully-coalesced dwordx4 (64 lanes x 16B = 1KB contiguous):
//   Kf[(((b*256 + t16)*2 + g)*64 + lane)*4 + jj]
//     holds pair-plane cp = g*16 + (lane>>4)*4 + jj at key = t16*16 + (lane&15)
//   Vf[(((b*128 + kb)*4 + mt)*64 + lane)*4 + w]
//     holds channel m = mt*16 + (lane&15), key-pair k = kb*16 + (lane>>4)*4 + w
__global__ __launch_bounds__(256) void pack_k(
    const float* __restrict__ z2s, const float* __restrict__ z2x,
    const float* __restrict__ z2y,
    const float* __restrict__ gs2, const float* __restrict__ bs2,
    const float* __restrict__ gx2, const float* __restrict__ bx2,
    const float* __restrict__ gy2, const float* __restrict__ by2,
    int* __restrict__ Qh, int* __restrict__ Kf, int* __restrict__ Vf,
    const float* __restrict__ stats) {
  const int job = blockIdx.z;  // 0: Q<-x2, 1: K<-y2, 2: V<-s2
  const int idx = blockIdx.x * 256 + threadIdx.x;  // 0..524287
  const float* z2 = job == 0 ? z2x : (job == 1 ? z2y : z2s);
  const float* g2 = job == 0 ? gx2 : (job == 1 ? gy2 : gs2);
  const float* b2 = job == 0 ? bx2 : (job == 1 ? by2 : bs2);
  const float* st = stats + (job == 0 ? 4 : (job == 1 ? 5 : 3)) * 128;
  int* outp = job == 0 ? Qh : (job == 1 ? Kf : Vf);

  auto snorm = [&](int c, float& s, float& h) {
    float mean = st[c] * (1.f / CNT);
    float var = st[64 + c] * (1.f / CNT) - mean * mean;
    float r = rsqrtf(var + 1e-5f);
    s = g2[c] * r;
    h = b2[c] - mean * s;
  };
  if (job == 0) {
    int n = idx & 4095, c = (idx >> 12) & 31, b = idx >> 17;
    float s0, h0, s1, h1;
    snorm(2 * c, s0, h0);
    snorm(2 * c + 1, s1, h1);
    float v0 = z2[((size_t)b * 64 + 2 * c) * N_ + n] * s0 + h0;
    float v1 = z2[((size_t)b * 64 + 2 * c + 1) * N_ + n] * s1 + h1;
    outp[idx] = pkh(v0, v1);
  } else if (job == 1) {
    int n = idx & 4095, c = (idx >> 12) & 31, b = idx >> 17;
    float s0, h0, s1, h1;
    snorm(2 * c, s0, h0);
    snorm(2 * c + 1, s1, h1);
    float v0 = z2[((size_t)b * 64 + 2 * c) * N_ + n] * s0 + h0;
    float v1 = z2[((size_t)b * 64 + 2 * c + 1) * N_ + n] * s1 + h1;
    int t16 = n >> 4, la = n & 15, g = c >> 4, quad = (c & 15) >> 2, jj = c & 3;
    outp[(((b * 256 + t16) * 2 + g) * 64 + quad * 16 + la) * 4 + jj] = pkh(v0, v1);
  } else {
    int k = idx & 2047, ch = (idx >> 11) & 63, b = idx >> 17;
    float s0, h0;
    snorm(ch, s0, h0);
    float2 v = *(const float2*)&z2[((size_t)b * 64 + ch) * N_ + 2 * k];
    int kb = k >> 4, p = k & 15, quad = p >> 2, w = p & 3, mt = ch >> 4, la = ch & 15;
    outp[(((b * 128 + kb) * 4 + mt) * 64 + quad * 16 + la) * 4 + w] =
        pkh(v.x * s0 + h0, v.y * s0 + h0);
  }
}

// ---------------- MFMA fp16 flash attention, S^T layout, coalesced frag loads ------
// K double-buffered in registers (prefetch next iter after QK^T); V issued at the
// top of the body so its L2 latency hides under the softmax/LDS chain. All K/V
// loads are 1KB coalesced dwordx4. Epilogue O tile padded to 69 (stride coprime 32).
__global__ __launch_bounds__(256, 4) void attn_k(const int* __restrict__ Qh,
                                                 const int* __restrict__ Kf,
                                                 const int* __restrict__ Vf,
                                                 float* __restrict__ fout) {
  const int tid = threadIdx.x;
  const int lane = tid & 63;
  const int wid = tid >> 6;
  const int la = lane & 15;
  const int quad = lane >> 4;
  const int b = blockIdx.x & 3;
  const int qbase = (blockIdx.x >> 2) * 16;
  const int* Qb = Qh + (size_t)b * 32 * N_;
  const int* Kb4 = Kf + (size_t)b * 131072;
  const int* Vb4 = Vf + (size_t)b * 131072;

  __shared__ union USm {
    int P16[4][16 * 20];  // per-wave packed P^T pairs: [pair 0..15][q 0..15] pad 20
    struct { float O[4][16][69]; float M[4][16]; float L[4][16]; } e;
  } smu;
  int* myP = smu.P16[wid];

  // Q fragment (B operand): col=lane&15=query qbase+la, k=channels
  fragh aq[2];
#pragma unroll
  for (int c = 0; c < 2; ++c)
#pragma unroll
    for (int j = 0; j < 4; ++j)
      aq[c].i4[j] = Qb[(size_t)(c * 16 + quad * 4 + j) * N_ + qbase + la];

  f32x4 o[4];
  float mrun = -3.0e38f, lrun = 0.f;
#pragma unroll
  for (int mt = 0; mt < 4; ++mt) o[mt] = f32x4{0.f, 0.f, 0.f, 0.f};

  const int jbeg = wid * (N_ / 4);
  const int jend = jbeg + N_ / 4;

  int4 ka[2][2], kb2[2][2];
#pragma unroll
  for (int nt = 0; nt < 2; ++nt)
#pragma unroll
    for (int g = 0; g < 2; ++g)
      ka[nt][g] = *(const int4*)&Kb4[((((jbeg >> 4) + nt) * 2 + g) * 64 + lane) * 4];

  auto body = [&](int j0, int4 (&kc)[2][2], int4 (&kn)[2][2]) {
    // S^T tiles from current K fragments
    f32x4 s[2];
#pragma unroll
    for (int nt = 0; nt < 2; ++nt) {
      fragh k0, k1;
      k0.i4[0] = kc[nt][0].x; k0.i4[1] = kc[nt][0].y;
      k0.i4[2] = kc[nt][0].z; k0.i4[3] = kc[nt][0].w;
      k1.i4[0] = kc[nt][1].x; k1.i4[1] = kc[nt][1].y;
      k1.i4[2] = kc[nt][1].z; k1.i4[3] = kc[nt][1].w;
      f32x4 z = f32x4{0.f, 0.f, 0.f, 0.f};
      z = __builtin_amdgcn_mfma_f32_16x16x32_f16(k0.h8, aq[0].h8, z, 0, 0, 0);
      s[nt] = __builtin_amdgcn_mfma_f32_16x16x32_f16(k1.h8, aq[1].h8, z, 0, 0, 0);
    }
    // V for THIS iter: issue now, consumed at the end (latency hidden by softmax)
    int4 vv[4];
#pragma unroll
    for (int mt = 0; mt < 4; ++mt)
      vv[mt] = *(const int4*)&Vb4[(((j0 >> 5) * 4 + mt) * 64 + lane) * 4];
    // K prefetch for NEXT iter (wraps harmlessly on the last one)
    const int nj = (j0 + 32 < jend) ? (j0 + 32) : jbeg;
#pragma unroll
    for (int nt = 0; nt < 2; ++nt)
#pragma unroll
      for (int g = 0; g < 2; ++g)
        kn[nt][g] = *(const int4*)&Kb4[((((nj >> 4) + nt) * 2 + g) * 64 + lane) * 4];
    // online softmax for query la
    float t0 = fmaxf(fmaxf(s[0][0], s[0][1]), fmaxf(s[0][2], s[0][3]));
    float t1 = fmaxf(fmaxf(s[1][0], s[1][1]), fmaxf(s[1][2], s[1][3]));
    float t = fmaxf(t0, t1);
    t = fmaxf(t, __shfl_xor(t, 16));
    t = fmaxf(t, __shfl_xor(t, 32));
    float mnew = fmaxf(mrun, t);
    float alpha = __expf(mrun - mnew);
    float p[2][4];
    float ps = 0.f;
#pragma unroll
    for (int nt = 0; nt < 2; ++nt)
#pragma unroll
      for (int r = 0; r < 4; ++r) {
        p[nt][r] = __expf(s[nt][r] - mnew);
        ps += p[nt][r];
      }
    ps += __shfl_xor(ps, 16);
    ps += __shfl_xor(ps, 32);
    lrun = lrun * alpha + ps;
    mrun = mnew;
    // pack P^T pairs and redistribute across quads via per-wave LDS table
#pragma unroll
    for (int nt = 0; nt < 2; ++nt) {
      myP[(nt * 8 + quad * 2 + 0) * 20 + la] = pkh(p[nt][0], p[nt][1]);
      myP[(nt * 8 + quad * 2 + 1) * 20 + la] = pkh(p[nt][2], p[nt][3]);
    }
    __asm__ __volatile__("s_waitcnt lgkmcnt(0)" ::: "memory");
    fragh pb;
#pragma unroll
    for (int j = 0; j < 4; ++j) pb.i4[j] = myP[(quad * 4 + j) * 20 + la];
    // rescale O^T by scalar alpha and accumulate PV^T
#pragma unroll
    for (int mt = 0; mt < 4; ++mt) {
      o[mt][0] *= alpha; o[mt][1] *= alpha;
      o[mt][2] *= alpha; o[mt][3] *= alpha;
    }
#pragma unroll
    for (int mt = 0; mt < 4; ++mt) {
      fragh vb;
      vb.i4[0] = vv[mt].x; vb.i4[1] = vv[mt].y;
      vb.i4[2] = vv[mt].z; vb.i4[3] = vv[mt].w;
      o[mt] = __builtin_amdgcn_mfma_f32_16x16x32_f16(vb.h8, pb.h8, o[mt], 0, 0, 0);
    }
  };

#pragma unroll 1
  for (int j0 = jbeg; j0 < jend; j0 += 64) {
    body(j0, ka, kb2);
    body(j0 + 32, kb2, ka);
  }

  __syncthreads();
  if (quad == 0) {
    smu.e.M[wid][la] = mrun;
    smu.e.L[wid][la] = lrun;
  }
  // O^T: o[mt][r] = O[m = mt*16+quad*4+r][q = la]
#pragma unroll
  for (int mt = 0; mt < 4; ++mt)
#pragma unroll
    for (int r = 0; r < 4; ++r) smu.e.O[wid][la][mt * 16 + quad * 4 + r] = o[mt][r];
  __syncthreads();

#pragma unroll
  for (int t = 0; t < 4; ++t) {
    int oidx = t * 256 + tid;
    int m = oidx >> 4;
    int q = oidx & 15;
    float m0 = fmaxf(fmaxf(smu.e.M[0][q], smu.e.M[1][q]),
                     fmaxf(smu.e.M[2][q], smu.e.M[3][q]));
    float num = 0.f, den = 0.f;
#pragma unroll
    for (int w = 0; w < 4; ++w) {
      float wgt = __expf(smu.e.M[w][q] - m0);
      num += wgt * smu.e.O[w][q][m];
      den += wgt * smu.e.L[w][q];
    }
    fout[((size_t)b * 64 + m) * N_ + qbase + q] = num / den;
  }
}

// ---------------- f_up conv (K=64, O=512): SGEMM tiling ----------------------------
__global__ __launch_bounds__(256) void convup_k(const float* __restrict__ fout,
                                                const float* __restrict__ wu,
                                                float* __restrict__ u,
                                                float* __restrict__ stats) {
  const int t = threadIdx.x;
  const int slice = blockIdx.x;
  const int b = slice >> 5;
  const int n0 = (slice & 31) * 128;
  const int o0 = blockIdx.y * 64;

  __shared__ float sA[32][132];
  __shared__ float sW[32][72];

  const int to = (t >> 5) * 8;
  const int tn = (t & 31) * 4;
  float acc[8][4];
#pragma unroll
  for (int i = 0; i < 8; ++i)
#pragma unroll
    for (int j = 0; j < 4; ++j) acc[i][j] = 0.f;

  const float* Ab = fout + (size_t)b * 64 * N_ + n0;
#pragma unroll 1
  for (int k0 = 0; k0 < 64; k0 += 32) {
    __syncthreads();
#pragma unroll
    for (int i = 0; i < 4; ++i) {
      int row = i * 8 + (t >> 5);
      float4 v = *(const float4*)&Ab[(size_t)(k0 + row) * N_ + tn];
      *(float4*)&sA[row][tn] = v;
    }
    {
      int o = t >> 2, kk = (t & 3) * 8;
      float4 w0 = *(const float4*)&wu[(size_t)(o0 + o) * 64 + k0 + kk];
      float4 w1 = *(const float4*)&wu[(size_t)(o0 + o) * 64 + k0 + kk + 4];
      sW[kk + 0][o] = w0.x; sW[kk + 1][o] = w0.y;
      sW[kk + 2][o] = w0.z; sW[kk + 3][o] = w0.w;
      sW[kk + 4][o] = w1.x; sW[kk + 5][o] = w1.y;
      sW[kk + 6][o] = w1.z; sW[kk + 7][o] = w1.w;
    }
    __syncthreads();
#pragma unroll
    for (int k = 0; k < 32; ++k) {
      float4 a = *(const float4*)&sA[k][tn];
      float4 w0 = *(const float4*)&sW[k][to];
      float4 w1 = *(const float4*)&sW[k][to + 4];
      float wv[8] = {w0.x, w0.y, w0.z, w0.w, w1.x, w1.y, w1.z, w1.w};
      float av[4] = {a.x, a.y, a.z, a.w};
#pragma unroll
      for (int i = 0; i < 8; ++i)
#pragma unroll
        for (int j = 0; j < 4; ++j) acc[i][j] += wv[i] * av[j];
    }
  }
  float* Cb = u + ((size_t)b * 512 + o0) * N_ + n0;
#pragma unroll
  for (int i = 0; i < 8; ++i) {
    float4 v = {acc[i][0], acc[i][1], acc[i][2], acc[i][3]};
    *(float4*)&Cb[(size_t)(to + i) * N_ + tn] = v;
  }
#pragma unroll
  for (int i = 0; i < 8; ++i) {
    float s = acc[i][0] + acc[i][1] + acc[i][2] + acc[i][3];
    float q = acc[i][0] * acc[i][0] + acc[i][1] * acc[i][1] +
              acc[i][2] * acc[i][2] + acc[i][3] * acc[i][3];
#pragma unroll
    for (int d = 1; d < 32; d <<= 1) { s += __shfl_xor(s, d); q += __shfl_xor(q, d); }
    if ((t & 31) == 0) {
      atomicAdd(&stats[768 + o0 + to + i], s);
      atomicAdd(&stats[1280 + o0 + to + i], q);
    }
  }
}

// ---------------- residual + final BN ----------------------------------------------
__global__ __launch_bounds__(256) void final_k(const float* __restrict__ x,
                                               const float* __restrict__ u,
                                               const float* __restrict__ gu,
                                               const float* __restrict__ bu,
                                               const float* __restrict__ stats,
                                               float* __restrict__ out) {
  size_t idx = (size_t)blockIdx.x * 256 + threadIdx.x;
  int c = (int)((idx >> 12) & 511);
  float mean = stats[768 + c] * (1.f / CNT);
  float var = stats[1280 + c] * (1.f / CNT) - mean * mean;
  float r = rsqrtf(var + 1e-5f);
  float s = gu[c] * r;
  float sh = bu[c] - mean * s;
  out[idx] = x[idx] + u[idx] * s + sh;
}

extern "C" void kernel_launch(void* const* d_in, const int* in_sizes, int n_in,
                              void* d_out, int out_size, void* d_ws, size_t ws_size,
                              hipStream_t stream) {
  const float* x = (const float*)d_in[0];
  const float* y = (const float*)d_in[1];
  const float* ws1 = (const float*)d_in[2];
  const float* gs1 = (const float*)d_in[3];
  const float* bs1 = (const float*)d_in[4];
  const float* ws2 = (const float*)d_in[5];
  const float* gs2 = (const float*)d_in[6];
  const float* bs2 = (const float*)d_in[7];
  const float* wx1 = (const float*)d_in[8];
  const float* gx1 = (const float*)d_in[9];
  const float* bx1 = (const float*)d_in[10];
  const float* wx2 = (const float*)d_in[11];
  const float* gx2 = (const float*)d_in[12];
  const float* bx2 = (const float*)d_in[13];
  const float* wy1 = (const float*)d_in[14];
  const float* gy1 = (const float*)d_in[15];
  const float* by1 = (const float*)d_in[16];
  const float* wy2 = (const float*)d_in[17];
  const float* gy2 = (const float*)d_in[18];
  const float* by2 = (const float*)d_in[19];
  const float* wu = (const float*)d_in[20];
  const float* gu = (const float*)d_in[21];
  const float* bu = (const float*)d_in[22];
  float* out = (float*)d_out;

  float* w = (float*)d_ws;
  const size_t M1 = 1048576;
  float* z1s = w + 0 * M1;
  float* z1x = w + 1 * M1;
  float* z1y = w + 2 * M1;
  float* z2s = w + 3 * M1;
  float* z2x = w + 4 * M1;
  float* z2y = w + 5 * M1;
  float* fout = w + 6 * M1;
  float* u = w + 7 * M1;  // [4][512][4096] = 8 M floats
  int* Qh = (int*)(w + 15 * M1);
  int* Kf = Qh + 524288;
  int* Vf = Kf + 524288;
  float* stats = (float*)(Vf + 524288);

  hipMemsetAsync(stats, 0, 1792 * sizeof(float), stream);

  conv1_k<<<dim3(128, 3), dim3(256), 0, stream>>>(x, y, ws1, wx1, wy1, z1s, z1x,
                                                  z1y, stats);
  conv2_k<<<dim3(128, 3), dim3(256), 0, stream>>>(
      z1s, z1x, z1y, ws2, wx2, wy2, gs1, bs1, gx1, bx1, gy1, by1, z2s, z2x, z2y,
      stats);
  pack_k<<<dim3(2048, 1, 3), dim3(256), 0, stream>>>(z2s, z2x, z2y, gs2, bs2, gx2,
                                                     bx2, gy2, by2, Qh, Kf, Vf,
                                                     stats);
  attn_k<<<dim3(1024), dim3(256), 0, stream>>>(Qh, Kf, Vf, fout);
  convup_k<<<dim3(128, 8), dim3(256), 0, stream>>>(fout, wu, u, stats);
  final_k<<<dim3(32768), dim3(256), 0, stream>>>(x, u, gu, bu, stats, out);
}